// Round 13
// baseline (143.744 us; speedup 1.0000x reference)
//
#include <hip/hip_runtime.h>
#include <hip/hip_bf16.h>

typedef __hip_bfloat16 bf16;
typedef short short8 __attribute__((ext_vector_type(8)));
typedef float f32x4 __attribute__((ext_vector_type(4)));

#define C_   128
#define N_   4096
#define NH_  8
#define HD_  16
#define FF_  2048
#define SCALE_Q 0.360673760222241f   // 0.25 * log2(e); attn uses v_exp_f32 (2^x)

__device__ __forceinline__ unsigned short f2bf_bits(float f) {
    bf16 h = __float2bfloat16(f);
    return *reinterpret_cast<unsigned short*>(&h);
}
__device__ __forceinline__ unsigned int pack_trunc(float lo, float hi) {
    return (__float_as_uint(hi) & 0xffff0000u) | (__float_as_uint(lo) >> 16);
}
__device__ __forceinline__ short f2bf_trunc(float f) {
    return (short)(__float_as_uint(f) >> 16);
}
__device__ __forceinline__ float bfs2f(short s) {
    return __uint_as_float(((unsigned int)(unsigned short)s) << 16);
}
__device__ __forceinline__ float fast_exp2(float x) {
    return __builtin_amdgcn_exp2f(x);
}
__device__ __forceinline__ f32x4 mfma16(short8 a, short8 b, f32x4 c) {
    return __builtin_amdgcn_mfma_f32_16x16x32_bf16(a, b, c, 0, 0, 0);
}

// ---------------- K0: prep — fragment blocks with fully-coalesced dwordx4 stores -----------
// R12 post-mortem: per-element 2-B scatter stores serialize in the TA pipe.
// Now one wave emits one 1 KB frag block: lane gathers the exact 8 (kpos-interleaved)
// values its consumer lane will read, stores 16 B contiguous at base+lane*16.
// W blocks (kpos order): gw 0..1151.  x blocks (kpos order, LDS-staged): gw 1152..2175.
__global__ void __launch_bounds__(256) k_prep(
    const float* __restrict__ Wq, const float* __restrict__ Wk,
    const float* __restrict__ Wv, const float* __restrict__ Wo,
    const float* __restrict__ W1, const float* __restrict__ W2,
    const float* __restrict__ x,
    bf16* __restrict__ Wqkvf, bf16* __restrict__ Wof,
    bf16* __restrict__ W1f, bf16* __restrict__ W2f,
    bf16* __restrict__ xTf)
{
    __shared__ float xs[4][512];                 // per-wave 2 KB staging (x path)
    const int tid = threadIdx.x, wave = tid >> 6, lane = tid & 63;
    const int gw = blockIdx.x * 4 + wave;        // [0, 2176)
    const int q = lane >> 4;

    if (gw < 1152) {
        const float* src; bf16* dst; int K, otile, kch, blk;
        if (gw < 96)        { src = 0;  dst = Wqkvf; K = 128;  otile = gw >> 2;          kch = gw & 3;  blk = gw; }
        else if (gw < 128)  { int i = gw - 96;  src = Wo; dst = Wof;  K = 128;  otile = i >> 2; kch = i & 3;  blk = i; }
        else if (gw < 640)  { int i = gw - 128; src = W1; dst = W1f;  K = 128;  otile = i >> 2; kch = i & 3;  blk = i; }
        else                { int i = gw - 640; src = W2; dst = W2f;  K = 2048; otile = i >> 6; kch = i & 63; blk = i; }
        const int o = otile * 16 + (lane & 15);
        const int k0 = kch * 32 + 4 * q;
        const float* row;
        if (gw < 96) {   // composite Wq|Wk|Wv
            row = (o < 128) ? (Wq + o * 128) : (o < 256) ? (Wk + (o - 128) * 128)
                                             : (Wv + (o - 256) * 128);
        } else {
            row = src + (size_t)o * K;
        }
        const float4 A = *(const float4*)(row + k0);
        const float4 B = *(const float4*)(row + k0 + 16);
        short8 v;
        v[0] = f2bf_bits(A.x); v[1] = f2bf_bits(B.x);
        v[2] = f2bf_bits(A.y); v[3] = f2bf_bits(B.y);
        v[4] = f2bf_bits(A.z); v[5] = f2bf_bits(B.z);
        v[6] = f2bf_bits(A.w); v[7] = f2bf_bits(B.w);
        *(short8*)((short*)dst + (size_t)blk * 512 + lane * 8) = v;
    } else {
        const int i = gw - 1152;                 // [0,1024): ntile*4 + cchunk
        const int n0 = (i >> 2) << 4, c0 = (i & 3) << 5;
        float* S = xs[wave];
        // stage x[c0..c0+32)[n0..n0+16) : lane -> row c0+(lane&31), 8 n's
        const int cl = lane & 31, ns = (lane >> 5) << 3;
        const float* p = x + (size_t)(c0 + cl) * N_ + n0 + ns;
        *(float4*)(S + cl * 16 + ns)     = *(const float4*)(p);
        *(float4*)(S + cl * 16 + ns + 4) = *(const float4*)(p + 4);
        // gather kpos-interleaved values for this lane's consumer position
        short8 v;
        #pragma unroll
        for (int j = 0; j < 8; ++j) {
            const int ko = ((j & 1) << 4) + 4 * q + (j >> 1);
            v[j] = f2bf_bits(S[ko * 16 + (lane & 15)]);
        }
        *(short8*)((short*)xTf + (size_t)i * 512 + lane * 8) = v;
    }
}

// ---------------- K1: QKV — frag-stream GEMM, contiguous epilogue stores ----------------
// qf/kf blocks: straight 16-ch layout. vf: NATURAL key order (pos = ko), so each
// 16-key wave fills a contiguous 512 B half-chunk. Epilogue: b16 LDS transpose
// then 32-lane dwordx4 store (replaces 16 scattered b16 global stores per wave).
__global__ void __launch_bounds__(256) k_qkv(
    const bf16* __restrict__ xTf, const bf16* __restrict__ Wqkvf,
    const float* __restrict__ bq, const float* __restrict__ bk, const float* __restrict__ bv,
    bf16* __restrict__ qf, bf16* __restrict__ kf, bf16* __restrict__ vf)
{
    __shared__ short tb[4][512];
    const int tid = threadIdx.x, wave = tid >> 6, lane = tid & 63;
    const int col = lane & 15, quad = lane >> 4;
    const int gw = blockIdx.x * 4 + wave;     // [0, 6144)
    const int rt = gw / 24, ct = gw % 24;
    f32x4 acc = {};
    #pragma unroll
    for (int c = 0; c < 4; ++c) {
        short8 a = *(const short8*)(xTf + ((size_t)(rt * 4 + c) << 9) + lane * 8);
        short8 b = *(const short8*)(Wqkvf + ((size_t)(ct * 4 + c) << 9) + lane * 8);
        acc = mfma16(a, b, acc);
    }
    short* T = tb[wave];
    if (ct < 8) {                  // Q, head h=ct
        const float bb = bq[ct * 16 + col];
        #pragma unroll
        for (int r = 0; r < 4; ++r)
            T[(col >> 3) * 128 + (quad * 4 + r) * 8 + (col & 7)] =
                f2bf_trunc((acc[r] + bb) * SCALE_Q);
    } else if (ct < 16) {          // K, head h=ct-8
        const float bb = bk[(ct - 8) * 16 + col];
        #pragma unroll
        for (int r = 0; r < 4; ++r)
            T[(col >> 3) * 128 + (quad * 4 + r) * 8 + (col & 7)] =
                f2bf_trunc(acc[r] + bb);
    } else {                       // V, head h=ct-16; rows are keys
        const float bb = bv[(ct - 16) * 16 + col];
        #pragma unroll
        for (int r = 0; r < 4; ++r) {
            const int ko = quad * 4 + r;
            T[(ko >> 3) * 128 + col * 8 + (ko & 7)] = f2bf_trunc(acc[r] + bb);
        }
    }
    if (lane < 32) {
        short8 w = *(const short8*)(T + lane * 8);
        short* dst;
        if (ct < 8)       dst = (short*)qf + ((ct << 8) + rt) * 256;
        else if (ct < 16) dst = (short*)kf + (((ct - 8) << 8) + rt) * 256;
        else              dst = (short*)vf + ((((ct - 16) << 7) + (rt >> 1)) << 9) + (rt & 1) * 256;
        *(short8*)(dst + lane * 8) = w;
    }
}

// ---------------- K2: MFMA flash attention — dual-chunk ILP, natural-order P ----------------
__global__ void __launch_bounds__(256)
attn_kernel(const bf16* __restrict__ qf, const bf16* __restrict__ kf,
            const bf16* __restrict__ vf, bf16* __restrict__ af)
{
    __shared__ __align__(16) union {
        unsigned int P[4][2][320];
        float comb[4][64][8];
    } sh;
    const int tid = threadIdx.x, wave = tid >> 6, lane = tid & 63;
    const int col = lane & 15, quad = lane >> 4;
    const int gw = blockIdx.x;                   // [0, 2048)
    const int h  = gw >> 8;
    const int tile = gw & 255;
    const f32x4 zero = {};

    short8 aq = {};
    if (quad < 2)
        aq = *(const short8*)(qf + ((size_t)((h << 8) + tile) << 8) + lane * 8);

    f32x4 accO0 = {}, accO1 = {};
    float L[4] = {0.f, 0.f, 0.f, 0.f};

    const int kbeg = wave << 10;
    short* P0 = (short*)&sh.P[wave][0][0];
    short* P1 = (short*)&sh.P[wave][1][0];

    for (int i = 0; i < 32; i += 2) {
        const int mA = kbeg + (i << 5);
        const int mB = mA + 32;

        short8 bkA0 = {}, bkA1 = {}, bkB0 = {}, bkB1 = {};
        if (quad < 2) {
            const bf16* ka = kf + ((size_t)((h << 8) + (mA >> 4)) << 8) + lane * 8;
            bkA0 = *(const short8*)(ka);
            bkA1 = *(const short8*)(ka + 256);
            bkB0 = *(const short8*)(ka + 512);
            bkB1 = *(const short8*)(ka + 768);
        }
        f32x4 s0 = mfma16(aq, bkA0, zero);
        f32x4 s1 = mfma16(aq, bkA1, zero);
        f32x4 s2 = mfma16(aq, bkB0, zero);
        f32x4 s3 = mfma16(aq, bkB1, zero);
        #pragma unroll
        for (int r = 0; r < 4; ++r) {
            const float p0 = fast_exp2(s0[r]);
            const float p1 = fast_exp2(s1[r]);
            const float p2 = fast_exp2(s2[r]);
            const float p3 = fast_exp2(s3[r]);
            L[r] += (p0 + p1) + (p2 + p3);
            const int row = (quad * 4 + r) * 40;
            P0[row + col]      = f2bf_trunc(p0);   // key mA+col
            P0[row + 16 + col] = f2bf_trunc(p1);   // key mA+16+col
            P1[row + col]      = f2bf_trunc(p2);
            P1[row + 16 + col] = f2bf_trunc(p3);
        }
        short8 vA = *(const short8*)(vf + ((size_t)((h << 7) + (mA >> 5)) << 9) + lane * 8);
        short8 vB = *(const short8*)(vf + ((size_t)((h << 7) + (mB >> 5)) << 9) + lane * 8);
        short8 ap0 = *(const short8*)(P0 + col * 40 + quad * 8);
        accO0 = mfma16(ap0, vA, accO0);
        short8 ap1 = *(const short8*)(P1 + col * 40 + quad * 8);
        accO1 = mfma16(ap1, vB, accO1);
    }

    f32x4 accO;
    #pragma unroll
    for (int r = 0; r < 4; ++r) accO[r] = accO0[r] + accO1[r];

    __syncthreads();
    #pragma unroll
    for (int r = 0; r < 4; ++r) {
        sh.comb[wave][lane][r]     = accO[r];
        sh.comb[wave][lane][4 + r] = L[r];
    }
    __syncthreads();

    if (wave == 0) {
        #pragma unroll
        for (int r = 0; r < 4; ++r) {
            float O = sh.comb[0][lane][r] + sh.comb[1][lane][r]
                    + sh.comb[2][lane][r] + sh.comb[3][lane][r];
            float l = sh.comb[0][lane][4+r] + sh.comb[1][lane][4+r]
                    + sh.comb[2][lane][4+r] + sh.comb[3][lane][4+r];
            l += __shfl_xor(l, 1); l += __shfl_xor(l, 2);
            l += __shfl_xor(l, 4); l += __shfl_xor(l, 8);
            const int row16 = quad * 4 + r;
            const int pk = (col << 1) + (h & 1);     // kpos order (pairs with Wof)
            af[((tile << 2) + (h >> 1)) * 512 + (((pk >> 3) << 4) + row16) * 8 + (pk & 7)] =
                __float2bfloat16(O / l);
        }
    }
}

// ---------------- K3: MEGA — oproj + LN1 + FFN1 + FFN2 + LN2 (R10/R12 proven shape) -------
__global__ void __launch_bounds__(256, 1)
k_mega(const bf16* __restrict__ af, const bf16* __restrict__ xTf,
       const bf16* __restrict__ Wof, const bf16* __restrict__ W1f, const bf16* __restrict__ W2f,
       const float* __restrict__ bo, const float* __restrict__ b1, const float* __restrict__ b2,
       const float* __restrict__ g1, const float* __restrict__ be1,
       const float* __restrict__ g2, const float* __restrict__ be2,
       float* __restrict__ out)
{
    __shared__ __align__(16) unsigned int Pb[4][2][320];   // per-wave transpose dbuf (10 KB)
    __shared__ float comb[96][64];                          // ffn2 partials, waves 1-3 (24 KB)
    const int tid = threadIdx.x, wave = tid >> 6, lane = tid & 63;
    const int col = lane & 15, quad = lane >> 4;
    const int rt = blockIdx.x, n0 = rt << 4;
    const f32x4 zero = {};

    // ---- oproj: D = attn_frag . Wo^T  (each wave redundantly) ----
    short8 ao[4], xt[4];
    #pragma unroll
    for (int c = 0; c < 4; ++c) {
        ao[c] = *(const short8*)(af  + ((size_t)(rt * 4 + c) << 9) + lane * 8);
        xt[c] = *(const short8*)(xTf + ((size_t)(rt * 4 + c) << 9) + lane * 8);
    }
    f32x4 d[8];
    #pragma unroll
    for (int t = 0; t < 8; ++t) d[t] = zero;
    #pragma unroll
    for (int t = 0; t < 8; ++t)
        #pragma unroll
        for (int c = 0; c < 4; ++c) {
            short8 b = *(const short8*)(Wof + ((size_t)(t * 4 + c) << 9) + lane * 8);
            d[t] = mfma16(ao[c], b, d[t]);
        }
    #pragma unroll
    for (int t = 0; t < 8; ++t) {
        const float bt = bo[t * 16 + col];
        #pragma unroll
        for (int r = 0; r < 4; ++r) d[t][r] += bt;
    }

    // ---- D->A transpose via wave-private LDS; add residual x ----
    float x1f[4][8];
    #pragma unroll
    for (int c = 0; c < 4; ++c) {
        unsigned int* Pw = &Pb[wave][c & 1][0];
        const short* Ps = (const short*)Pw;
        #pragma unroll
        for (int r = 0; r < 4; ++r)
            Pw[(quad * 4 + r) * 20 + col] = pack_trunc(d[2 * c][r], d[2 * c + 1][r]);
        short8 ar = *(const short8*)(Ps + col * 40 + quad * 8);
        #pragma unroll
        for (int j = 0; j < 8; ++j)
            x1f[c][j] = bfs2f(ar[j]) + bfs2f(xt[c][j]);
    }

    // ---- LN1 ----
    float s = 0.f, ss = 0.f;
    #pragma unroll
    for (int c = 0; c < 4; ++c)
        #pragma unroll
        for (int j = 0; j < 8; ++j) { s += x1f[c][j]; ss += x1f[c][j] * x1f[c][j]; }
    s  += __shfl_xor(s, 16);  s  += __shfl_xor(s, 32);
    ss += __shfl_xor(ss, 16); ss += __shfl_xor(ss, 32);
    const float m1 = s * (1.f / 128.f);
    const float rstd1 = rsqrtf(ss * (1.f / 128.f) - m1 * m1 + 1e-5f);
    short8 aq1[4];
    #pragma unroll
    for (int c = 0; c < 4; ++c)
        #pragma unroll
        for (int j = 0; j < 8; ++j) {
            const int pos = quad * 8 + j;
            const int ko = ((pos & 1) << 4) + (pos >> 1);
            const int ch = c * 32 + ko;
            aq1[c][j] = f2bf_trunc((x1f[c][j] - m1) * rstd1 * g1[ch] + be1[ch]);
        }

    // ---- FFN: this wave owns FF range [wave*512, +512) = 16 chunks of 32 ----
    f32x4 ACC[8];
    #pragma unroll
    for (int t = 0; t < 8; ++t) ACC[t] = zero;
    for (int i = 0; i < 16; ++i) {
        const int ffc = (wave << 4) + i;
        f32x4 p0 = zero, p1 = zero;
        #pragma unroll
        for (int c = 0; c < 4; ++c) {
            short8 b = *(const short8*)(W1f + ((size_t)(ffc * 8 + c) << 9) + lane * 8);
            p0 = mfma16(aq1[c], b, p0);
        }
        #pragma unroll
        for (int c = 0; c < 4; ++c) {
            short8 b = *(const short8*)(W1f + ((size_t)(ffc * 8 + 4 + c) << 9) + lane * 8);
            p1 = mfma16(aq1[c], b, p1);
        }
        const float bb0 = b1[ffc * 32 + col], bb1 = b1[ffc * 32 + 16 + col];
        unsigned int* Pw = &Pb[wave][i & 1][0];
        #pragma unroll
        for (int r = 0; r < 4; ++r)
            Pw[(quad * 4 + r) * 20 + col] =
                pack_trunc(fmaxf(p0[r] + bb0, 0.f), fmaxf(p1[r] + bb1, 0.f));
        short8 ah = *(const short8*)((const short*)Pw + col * 40 + quad * 8);
        #pragma unroll
        for (int t = 0; t < 8; ++t) {
            short8 bw = *(const short8*)(W2f + ((size_t)(t * 64 + ffc) << 9) + lane * 8);
            ACC[t] = mfma16(ah, bw, ACC[t]);
        }
    }

    // ---- combine ffn2 partials; wave0: residual + LN2 + store ----
    if (wave) {
        #pragma unroll
        for (int t = 0; t < 8; ++t)
            #pragma unroll
            for (int r = 0; r < 4; ++r)
                comb[(wave - 1) * 32 + t * 4 + r][lane] = ACC[t][r];
    }
    __syncthreads();
    if (wave == 0) {
        #pragma unroll
        for (int t = 0; t < 8; ++t)
            #pragma unroll
            for (int r = 0; r < 4; ++r)
                ACC[t][r] += comb[t * 4 + r][lane] + comb[32 + t * 4 + r][lane]
                           + comb[64 + t * 4 + r][lane];
        short* xb = (short*)&Pb[0][0][0];
        #pragma unroll
        for (int c = 0; c < 4; ++c)
            *(short8*)(xb + (col * 4 + c) * 32 + quad * 8) = aq1[c];
        float t2[8][4];
        #pragma unroll
        for (int t = 0; t < 8; ++t) {
            const int ch = t * 16 + col;
            const int pk = (col << 1) + (t & 1);
            const int c = t >> 1;
            const float bb = b2[ch];
            #pragma unroll
            for (int r = 0; r < 4; ++r)
                t2[t][r] = ACC[t][r] + bb + bfs2f(xb[((quad * 4 + r) * 4 + c) * 32 + pk]);
        }
        #pragma unroll
        for (int r = 0; r < 4; ++r) {
            float S = 0.f, SS = 0.f;
            #pragma unroll
            for (int t = 0; t < 8; ++t) { S += t2[t][r]; SS += t2[t][r] * t2[t][r]; }
            S  += __shfl_xor(S, 1);  S  += __shfl_xor(S, 2);
            S  += __shfl_xor(S, 4);  S  += __shfl_xor(S, 8);
            SS += __shfl_xor(SS, 1); SS += __shfl_xor(SS, 2);
            SS += __shfl_xor(SS, 4); SS += __shfl_xor(SS, 8);
            const float m2 = S * (1.f / 128.f);
            const float rstd2 = rsqrtf(SS * (1.f / 128.f) - m2 * m2 + 1e-5f);
            #pragma unroll
            for (int t = 0; t < 8; ++t) {
                const int ch = t * 16 + col;
                out[(size_t)ch * N_ + n0 + quad * 4 + r] =
                    (t2[t][r] - m2) * rstd2 * g2[ch] + be2[ch];
            }
        }
    }
}

extern "C" void kernel_launch(void* const* d_in, const int* in_sizes, int n_in,
                              void* d_out, int out_size, void* d_ws, size_t ws_size,
                              hipStream_t stream) {
    const float* x   = (const float*)d_in[0];
    const float* Wq  = (const float*)d_in[1];
    const float* bq  = (const float*)d_in[2];
    const float* Wk  = (const float*)d_in[3];
    const float* bk  = (const float*)d_in[4];
    const float* Wv  = (const float*)d_in[5];
    const float* bv  = (const float*)d_in[6];
    const float* Wo  = (const float*)d_in[7];
    const float* bo  = (const float*)d_in[8];
    const float* W1  = (const float*)d_in[9];
    const float* b1  = (const float*)d_in[10];
    const float* W2  = (const float*)d_in[11];
    const float* b2  = (const float*)d_in[12];
    const float* g1  = (const float*)d_in[13];
    const float* be1 = (const float*)d_in[14];
    const float* g2  = (const float*)d_in[15];
    const float* be2 = (const float*)d_in[16];
    float* out = (float*)d_out;

    char* ws = (char*)d_ws;
    bf16* xTf   = (bf16*)(ws + 0);          // 1 MB
    bf16* qf    = (bf16*)(ws + 1048576);    // 1 MB
    bf16* kf    = (bf16*)(ws + 2097152);    // 1 MB
    bf16* vf    = (bf16*)(ws + 3145728);    // 1 MB (natural key order)
    bf16* af    = (bf16*)(ws + 4194304);    // 1 MB
    bf16* Wqkvf = (bf16*)(ws + 5242880);    // 96 KB
    bf16* Wof   = (bf16*)(ws + 5341184);    // 32 KB
    bf16* W1f   = (bf16*)(ws + 5373952);    // 512 KB
    bf16* W2f   = (bf16*)(ws + 5898240);    // 512 KB

    k_prep<<<544, 256, 0, stream>>>(Wq, Wk, Wv, Wo, W1, W2, x, Wqkvf, Wof, W1f, W2f, xTf);
    k_qkv<<<1536, 256, 0, stream>>>(xTf, Wqkvf, bq, bk, bv, qf, kf, vf);
    attn_kernel<<<2048, 256, 0, stream>>>(qf, kf, vf, af);
    k_mega<<<256, 256, 0, stream>>>(af, xTf, Wof, W1f, W2f, bo, b1, b2,
                                    g1, be1, g2, be2, out);
}